// Round 1
// baseline (8156.852 us; speedup 1.0000x reference)
//
#include <hip/hip_runtime.h>
#include <math.h>

// Problem constants
#define BB 32
#define VV 3
#define SS 106
#define TIN 30
#define WID 32
#define MOD 16
#define NL 6
#define NPIX (SS*SS)            // 11236
#define NCH (BB*WID*VV)         // 3072 channels of h
#define KX 32                   // selected kx modes (16 low + 16 high)
#define WLAYER (WID*WID*VV*VV*MOD*MOD)  // 2359296 per-layer spec weight elems

// ---------------- twiddle tables ----------------
// taby  [y][ky][2]   (cos,sin) of 2*pi*y*ky/106           (forward y-DFT)
// tabyT [ky][y][2]                                         (inverse y-DFT)
// tabx  [x][k][2]    (cos,sin) of 2*pi*x*kx/106, kx=k<16?k:k+74   (fwd x)
// tabxT [k][x][2]                                          (inverse x)
__global__ void k_tables(float* taby, float* tabyT, float* tabx, float* tabxT) {
    int i = blockIdx.x * blockDim.x + threadIdx.x;
    const double TWO_PI = 6.283185307179586476925286766559;
    if (i < SS*MOD) {
        int y = i >> 4, ky = i & 15;
        double th = TWO_PI * (double)y * (double)ky / (double)SS;
        float c = (float)cos(th), s = (float)sin(th);
        taby[i*2] = c; taby[i*2+1] = s;
        tabyT[(ky*SS + y)*2] = c; tabyT[(ky*SS + y)*2+1] = s;
    }
    if (i < SS*KX) {
        int x = i >> 5, k = i & 31;
        int kx = (k < 16) ? k : (k + 74);   // 90..105
        double th = TWO_PI * (double)x * (double)kx / (double)SS;
        float c = (float)cos(th), s = (float)sin(th);
        tabx[i*2] = c; tabx[i*2+1] = s;
        tabxT[(k*SS + x)*2] = c; tabxT[(k*SS + x)*2+1] = s;
    }
}

// ---------------- fc0 (lift) ----------------
// grid: B*V*S blocks (b,v,x). block 256.
// h[b][w][v][x][y] = sum_t x[b,v,x,y,t]*fw[t][w] + gx*fw[30][w] + gy*fw[31][w] + fb[w]
__global__ void k_fc0(const float* __restrict__ xin, const float* __restrict__ gridx,
                      const float* __restrict__ gridy, const float* __restrict__ fw,
                      const float* __restrict__ fb, float* __restrict__ h) {
    int blk = blockIdx.x;
    int xr = blk % SS; int bv = blk / SS; int v = bv % VV; int b = bv / VV;
    __shared__ float sx[SS*TIN];
    __shared__ float sw[32*WID];
    __shared__ float sb[WID];
    __shared__ float sgy[SS];
    const float* xrow = xin + ((size_t)(b*VV + v)*SS + xr) * (size_t)(SS*TIN);
    for (int i = threadIdx.x; i < SS*TIN; i += 256) sx[i] = xrow[i];
    for (int i = threadIdx.x; i < 32*WID; i += 256) sw[i] = fw[i];
    if (threadIdx.x < WID) sb[threadIdx.x] = fb[threadIdx.x];
    for (int i = threadIdx.x; i < SS; i += 256) sgy[i] = gridy[i];
    __syncthreads();
    float gx = gridx[xr];
    int y = threadIdx.x & 127;
    int wg = threadIdx.x >> 7;   // 0..1
    if (y < SS) {
        float gy = sgy[y];
        for (int w = wg; w < WID; w += 2) {
            float acc = sb[w] + gx * sw[30*WID + w] + gy * sw[31*WID + w];
            #pragma unroll
            for (int t = 0; t < TIN; t++) acc += sx[y*TIN + t] * sw[t*WID + w];
            h[((((size_t)b*WID + w)*VV + v)*SS + xr)*SS + y] = acc;
        }
    }
}

// ---------------- stage A: forward y-DFT ----------------
// grid: NCH blocks (ch = (b*32+c)*3+v). A[ch][x][ky][2]
__global__ void k_A(const float* __restrict__ h, const float* __restrict__ taby,
                    float* __restrict__ A) {
    int ch = blockIdx.x;
    __shared__ float simg[NPIX];   // 44.9 KB
    const float* img = h + (size_t)ch * NPIX;
    for (int i = threadIdx.x; i < NPIX; i += 256) simg[i] = img[i];
    __syncthreads();
    int ky = threadIdx.x & 15;
    int xg = threadIdx.x >> 4;    // 0..15
    const float2* tv = (const float2*)taby;
    for (int xb = xg; xb < SS; xb += 16) {
        float ar = 0.f, ai = 0.f;
        for (int y = 0; y < SS; y++) {
            float hv = simg[xb*SS + y];
            float2 t = tv[y*MOD + ky];
            ar += hv * t.x;
            ai -= hv * t.y;
        }
        float2* Ao = (float2*)(A + ((size_t)ch*SS + xb) * (MOD*2));
        Ao[ky] = make_float2(ar, ai);
    }
}

// ---------------- stage B: forward x-DFT ----------------
// grid: NCH blocks. hf[ch][kxi][ky][2], ch = b*96 + (c*3+v)
__global__ void k_B(const float* __restrict__ A, const float* __restrict__ tabx,
                    float* __restrict__ hf) {
    int ch = blockIdx.x;
    __shared__ float sA[SS*MOD*2];  // 13.6 KB  [x][ky][2]
    const float* Arow = A + (size_t)ch * (SS*MOD*2);
    for (int i = threadIdx.x; i < SS*MOD*2; i += 256) sA[i] = Arow[i];
    __syncthreads();
    int ky = threadIdx.x & 15;
    int kq = threadIdx.x >> 4;     // 0..15
    const float2* tv = (const float2*)tabx;
    for (int kxi = kq; kxi < KX; kxi += 16) {
        float hr = 0.f, hi = 0.f;
        for (int xx = 0; xx < SS; xx++) {
            float2 a = *(const float2*)&sA[(xx*MOD + ky)*2];
            float2 t = tv[xx*KX + kxi];
            // (ar + i ai) * (c - i s)
            hr += a.x * t.x + a.y * t.y;
            hi += a.y * t.x - a.x * t.y;
        }
        float2* out = (float2*)(hf + ((size_t)ch*KX + kxi) * (MOD*2));
        out[ky] = make_float2(hr, hi);
    }
}

// ---------------- stage C: mode mixing ----------------
// grid: (kxi=32, jqc=6); block 256.  oft[b][jq][kxi][ky][2]
__global__ void k_C(const float* __restrict__ hf,
                    const float* __restrict__ w1r, const float* __restrict__ w1i,
                    const float* __restrict__ w2r, const float* __restrict__ w2i,
                    float* __restrict__ oft) {
    int kxi = blockIdx.x;
    int jqc = blockIdx.y;
    int ky  = threadIdx.x & 15;
    int jql = threadIdx.x >> 4;    // 0..15
    int jq  = jqc*16 + jql;
    int j = jq / 3, q = jq % 3;
    const float* wr; const float* wi; int kxm;
    if (kxi < 16) { wr = w1r; wi = w1i; kxm = kxi; }
    else          { wr = w2r; wi = w2i; kxm = kxi - 16; }

    float accr[BB], acci[BB];
    #pragma unroll
    for (int b = 0; b < BB; b++) { accr[b] = 0.f; acci[b] = 0.f; }

    __shared__ float shf[256*36];   // [ipl*32+b][36] padded rows, 36 KB
    for (int ip0 = 0; ip0 < 96; ip0 += 8) {
        __syncthreads();
        {
            int r = threadIdx.x;       // 0..255
            int ipl = r >> 5; int b = r & 31;
            const float* src = hf + (((size_t)(b*96 + ip0 + ipl)*KX + kxi) * (MOD*2));
            float4* d4 = (float4*)&shf[r*36];
            const float4* s4 = (const float4*)src;
            #pragma unroll
            for (int t = 0; t < 8; t++) d4[t] = s4[t];
        }
        __syncthreads();
        #pragma unroll
        for (int ipl = 0; ipl < 8; ipl++) {
            int ip = ip0 + ipl;
            int iw = ip / 3, p = ip % 3;
            size_t widx = (((((size_t)iw*WID + j)*VV + p)*VV + q)*MOD + kxm)*MOD + ky;
            float wrv = wr[widx];
            float wiv = wi[widx];
            #pragma unroll
            for (int b = 0; b < BB; b++) {
                float2 hv = *(const float2*)&shf[(ipl*32 + b)*36 + ky*2];
                accr[b] += hv.x * wrv - hv.y * wiv;
                acci[b] += hv.x * wiv + hv.y * wrv;
            }
        }
    }
    #pragma unroll
    for (int b = 0; b < BB; b++) {
        float2* out = (float2*)(oft + (((size_t)(b*96 + jq)*KX + kxi) * (MOD*2)));
        out[ky] = make_float2(accr[b], acci[b]);
    }
}

// ---------------- stage D: inverse x-DFT ----------------
// grid: NCH blocks (ch2 = b*96 + jq). G[ch2][x][ky][2]
__global__ void k_D(const float* __restrict__ oft, const float* __restrict__ tabxT,
                    float* __restrict__ G) {
    int ch = blockIdx.x;
    __shared__ float so[KX*MOD*2];  // 4 KB [kxi][ky][2]
    const float* src = oft + (size_t)ch * (KX*MOD*2);
    for (int i = threadIdx.x; i < KX*MOD*2; i += 256) so[i] = src[i];
    __syncthreads();
    int ky = threadIdx.x & 15;
    int xg = threadIdx.x >> 4;
    const float2* tv = (const float2*)tabxT;
    for (int xx = xg; xx < SS; xx += 16) {
        float gr = 0.f, gi = 0.f;
        #pragma unroll
        for (int k = 0; k < KX; k++) {
            float2 o = *(const float2*)&so[(k*MOD + ky)*2];
            float2 t = tv[k*SS + xx];
            // (or + i oi) * (c + i s)
            gr += o.x * t.x - o.y * t.y;
            gi += o.x * t.y + o.y * t.x;
        }
        float2* out = (float2*)(G + ((size_t)ch*SS + xx) * (MOD*2));
        out[ky] = make_float2(gr, gi);
    }
}

// ---------------- stage E: inverse y-DFT + 1x1 conv + bias (+ gelu) ----------------
// grid: B*V*S blocks (b,v,x). block 256.
__global__ void k_E(const float* __restrict__ G, const float* __restrict__ hold,
                    const float* __restrict__ tabyT,
                    const float* __restrict__ cw, const float* __restrict__ cb,
                    float* __restrict__ hnew, int do_gelu) {
    int blk = blockIdx.x;
    int xr = blk % SS; int bv = blk / SS; int v = bv % VV; int b = bv / VV;
    __shared__ float sG[WID*MOD*2];   // [j][ky][2] 4 KB
    __shared__ float sh[WID*SS];      // [c][y] 13.6 KB
    __shared__ float scw[WID*WID];    // [j][c] 4 KB
    for (int i = threadIdx.x; i < WID*MOD*2; i += 256) {
        int j = i >> 5, e = i & 31;
        sG[i] = G[(((size_t)(b*96 + j*3 + v))*SS + xr)*(MOD*2) + e];
    }
    for (int i = threadIdx.x; i < WID*SS; i += 256) {
        int c = i / SS, y = i % SS;
        sh[i] = hold[((((size_t)b*WID + c)*VV + v)*SS + xr)*SS + y];
    }
    for (int i = threadIdx.x; i < WID*WID; i += 256) scw[i] = cw[i];
    __syncthreads();
    const float norm = 1.0f / (float)NPIX;
    int y = threadIdx.x & 127;
    int jg = threadIdx.x >> 7;   // 0..1
    if (y < SS) {
        const float2* tv = (const float2*)tabyT;
        for (int j = jg; j < WID; j += 2) {
            float s = sG[j*32 + 0];        // Re(G[x][0]); imag of DC bin discarded
            #pragma unroll
            for (int ky = 1; ky < MOD; ky++) {
                float2 t = tv[ky*SS + y];
                s += 2.f * (sG[j*32 + ky*2] * t.x - sG[j*32 + ky*2 + 1] * t.y);
            }
            float acc = s * norm + cb[j];
            #pragma unroll
            for (int c = 0; c < WID; c++) acc += sh[c*SS + y] * scw[j*WID + c];
            if (do_gelu) acc = 0.5f * acc * (1.f + erff(acc * 0.70710678118654752440f));
            hnew[((((size_t)b*WID + j)*VV + v)*SS + xr)*SS + y] = acc;
        }
    }
}

// ---------------- head: fc1 + gelu + fc2 ----------------
// grid: B*V*S blocks. block 128.
__global__ void k_head(const float* __restrict__ h, const float* __restrict__ fc1w,
                       const float* __restrict__ fc1b, const float* __restrict__ fc2w,
                       const float* __restrict__ fc2b, float* __restrict__ out) {
    int blk = blockIdx.x;
    int xr = blk % SS; int bv = blk / SS; int v = bv % VV; int b = bv / VV;
    __shared__ float sh[WID*SS];     // 13.6 KB
    __shared__ float sw1[WID*128];   // 16 KB
    __shared__ float sb1[128];
    __shared__ float sw2[128];
    for (int i = threadIdx.x; i < WID*SS; i += 128) {
        int c = i / SS, y = i % SS;
        sh[i] = h[((((size_t)b*WID + c)*VV + v)*SS + xr)*SS + y];
    }
    for (int i = threadIdx.x; i < WID*128; i += 128) sw1[i] = fc1w[i];
    if (threadIdx.x < 128) { sb1[threadIdx.x] = fc1b[threadIdx.x]; sw2[threadIdx.x] = fc2w[threadIdx.x]; }
    __syncthreads();
    int y = threadIdx.x;
    if (y < SS) {
        float hr[WID];
        #pragma unroll
        for (int c = 0; c < WID; c++) hr[c] = sh[c*SS + y];
        float acc = fc2b[0];
        for (int k = 0; k < 128; k++) {
            float s = sb1[k];
            #pragma unroll
            for (int c = 0; c < WID; c++) s += hr[c] * sw1[c*128 + k];
            s = 0.5f * s * (1.f + erff(s * 0.70710678118654752440f));
            acc += s * sw2[k];
        }
        out[((size_t)(b*VV + v)*SS + xr)*SS + y] = acc;
    }
}

extern "C" void kernel_launch(void* const* d_in, const int* in_sizes, int n_in,
                              void* d_out, int out_size, void* d_ws, size_t ws_size,
                              hipStream_t stream) {
    const float* xin   = (const float*)d_in[0];
    const float* gridx = (const float*)d_in[1];
    const float* gridy = (const float*)d_in[2];
    const float* fc0w  = (const float*)d_in[3];
    const float* fc0b  = (const float*)d_in[4];
    const float* w1r   = (const float*)d_in[5];
    const float* w1i   = (const float*)d_in[6];
    const float* w2r   = (const float*)d_in[7];
    const float* w2i   = (const float*)d_in[8];
    const float* convw = (const float*)d_in[9];
    const float* convb = (const float*)d_in[10];
    const float* fc1w  = (const float*)d_in[11];
    const float* fc1b  = (const float*)d_in[12];
    const float* fc2w  = (const float*)d_in[13];
    const float* fc2b  = (const float*)d_in[14];
    float* out = (float*)d_out;

    float* p = (float*)d_ws;
    float* taby  = p; p += SS*MOD*2;        // 3392
    float* tabyT = p; p += SS*MOD*2;        // 3392
    float* tabx  = p; p += SS*KX*2;         // 6784
    float* tabxT = p; p += SS*KX*2;         // 6784
    float* h0   = p; p += (size_t)NCH * NPIX;       // 34,516,992
    float* h1   = p; p += (size_t)NCH * NPIX;       // 34,516,992
    float* Abuf = p; p += (size_t)NCH * SS * MOD*2; // 10,420,224 (shared with G)
    float* hfb  = p; p += (size_t)NCH * KX * MOD*2; // 3,145,728
    float* oftb = p; p += (size_t)NCH * KX * MOD*2; // 3,145,728

    k_tables<<<14, 256, 0, stream>>>(taby, tabyT, tabx, tabxT);
    k_fc0<<<BB*VV*SS, 256, 0, stream>>>(xin, gridx, gridy, fc0w, fc0b, h0);

    float* hc = h0; float* hn = h1;
    for (int L = 0; L < NL; L++) {
        k_A<<<NCH, 256, 0, stream>>>(hc, taby, Abuf);
        k_B<<<NCH, 256, 0, stream>>>(Abuf, tabx, hfb);
        k_C<<<dim3(KX, 6), 256, 0, stream>>>(hfb,
            w1r + (size_t)L*WLAYER, w1i + (size_t)L*WLAYER,
            w2r + (size_t)L*WLAYER, w2i + (size_t)L*WLAYER, oftb);
        k_D<<<NCH, 256, 0, stream>>>(oftb, tabxT, Abuf);
        k_E<<<BB*VV*SS, 256, 0, stream>>>(Abuf, hc, tabyT,
            convw + (size_t)L*WID*WID, convb + (size_t)L*WID, hn, (L < 3) ? 1 : 0);
        float* tmp = hc; hc = hn; hn = tmp;
    }
    k_head<<<BB*VV*SS, 128, 0, stream>>>(hc, fc1w, fc1b, fc2w, fc2b, out);
}

// Round 2
// 5510.800 us; speedup vs baseline: 1.4802x; 1.4802x over previous
//
#include <hip/hip_runtime.h>
#include <math.h>

#define BB 32
#define VV 3
#define SS 106
#define TIN 30
#define WID 32
#define MOD 16
#define NL 6
#define NPIX (SS*SS)
#define KX 32
#define WLAYER (WID*WID*VV*VV*MOD*MOD)
#define ROWF (SS*WID)          // 3392 floats per (b,v,x) row of h
#define AESZ 1024              // floats per (b,v,x) slice of A/G

// ---------------- twiddle tables ----------------
// taby  [y][ky][2] (cos,sin) of 2*pi*y*ky/106
// tabx  [x][k][2]  kx = k<16 ? k : k+74
// tabxTr/[k][x], tabxTi[k][x]
__global__ void k_tables(float* taby, float* tabx, float* tabxTr, float* tabxTi) {
    int i = blockIdx.x * blockDim.x + threadIdx.x;
    const double TWO_PI = 6.283185307179586476925286766559;
    if (i < SS*MOD) {
        int y = i >> 4, ky = i & 15;
        double th = TWO_PI * (double)y * (double)ky / (double)SS;
        taby[i*2] = (float)cos(th); taby[i*2+1] = (float)sin(th);
    }
    if (i < SS*KX) {
        int x = i >> 5, k = i & 31;
        int kx = (k < 16) ? k : (k + 74);
        double th = TWO_PI * (double)x * (double)kx / (double)SS;
        float c = (float)cos(th), s = (float)sin(th);
        tabx[i*2] = c; tabx[i*2+1] = s;
        tabxTr[k*SS + x] = c; tabxTi[k*SS + x] = s;
    }
}

// ---------------- fc0 (lift) + forward y-DFT ----------------
// grid B*V*S (b,v,xr). h channel-last: h[((b*3+v)*106+xr)*3392 + y*32 + c]
// A[((b*3+v)*106+xr)*1024 + c*32 + ky*2 + ri]
__global__ void k_fc0A(const float* __restrict__ xin, const float* __restrict__ gridx,
                       const float* __restrict__ gridy, const float* __restrict__ fw,
                       const float* __restrict__ fb, const float* __restrict__ taby,
                       float* __restrict__ h, float* __restrict__ A) {
    int blk = blockIdx.x;
    int xr = blk % SS; int bv = blk / SS; int v = bv % VV; int b = bv / VV;
    __shared__ float sx[SS*31];     // [y][30] pad 31
    __shared__ float sw[32*WID];
    __shared__ float sty[SS*33];    // taby rows padded 33
    __shared__ float sE[SS*33];     // output rows padded 33
    __shared__ float sb[WID];
    const float* xrow = xin + ((size_t)(b*VV + v)*SS + xr) * (size_t)(SS*TIN);
    for (int i = threadIdx.x; i < SS*TIN; i += 256) sx[(i/30)*31 + (i%30)] = xrow[i];
    for (int i = threadIdx.x; i < 32*WID; i += 256) sw[i] = fw[i];
    for (int i = threadIdx.x; i < SS*32; i += 256) sty[(i>>5)*33 + (i&31)] = taby[i];
    if (threadIdx.x < WID) sb[threadIdx.x] = fb[threadIdx.x];
    __syncthreads();
    float gx = gridx[xr];
    int y = threadIdx.x & 127;
    int wg = threadIdx.x >> 7;
    if (y < SS) {
        float gy = gridy[y];
        for (int w = wg; w < WID; w += 2) {
            float acc = sb[w] + gx * sw[30*WID + w] + gy * sw[31*WID + w];
            #pragma unroll
            for (int t = 0; t < TIN; t++) acc += sx[y*31 + t] * sw[t*WID + w];
            sE[y*33 + w] = acc;
        }
    }
    __syncthreads();
    // write h row (contiguous)
    float* hbase = h + (size_t)blk * ROWF;
    for (int i = threadIdx.x*4; i < ROWF; i += 1024)
        *(float4*)(hbase + i) = *(const float4*)&sE[i + (i>>5)];
    // forward y-DFT: A[c][ky] = sum_y sE[y][c] * e^{-i...}
    {
        int j = threadIdx.x & 31;
        int kyg = threadIdx.x >> 5;   // 0..7
        float r0=0.f,i0=0.f,r1=0.f,i1=0.f;
        int ky0 = kyg*2;
        for (int yy = 0; yy < SS; yy++) {
            float hv = sE[yy*33 + j];
            float c0 = sty[yy*33 + 2*ky0],   s0 = sty[yy*33 + 2*ky0+1];
            float c1 = sty[yy*33 + 2*ky0+2], s1 = sty[yy*33 + 2*ky0+3];
            r0 += hv*c0; i0 -= hv*s0;
            r1 += hv*c1; i1 -= hv*s1;
        }
        // stage to sx (reuse) then contiguous write
        float4* dst = (float4*)&sx[j*32 + kyg*4];
        *dst = make_float4(r0, i0, r1, i1);
    }
    __syncthreads();
    float* Abase = A + (size_t)blk * AESZ;
    for (int i = threadIdx.x*4; i < AESZ; i += 1024)
        *(float4*)(Abase + i) = *(const float4*)&sx[i];
}

// ---------------- stage B: forward x-DFT ----------------
// grid 384: blk -> cg(4), v(3), b(32). Reads A, writes hf[b][kx][ky][ip][2]
__global__ void k_B(const float* __restrict__ A, const float* __restrict__ tabx,
                    float* __restrict__ hf) {
    int blk = blockIdx.x;
    int cg = blk & 3; int v = (blk >> 2) % 3; int b = blk / 12;
    __shared__ float stx[SS*64];    // tabx [x][kx][2] 27136 B
    __shared__ float sAx[8*256];    // 8 x-rows of [c8][ky][2]
    for (int i = threadIdx.x; i < SS*64; i += 256) stx[i] = tabx[i];
    int kxh = threadIdx.x >> 7;        // 0..1
    int ky  = (threadIdx.x >> 3) & 15;
    int c   = threadIdx.x & 7;
    float ar[16], ai[16];
    #pragma unroll
    for (int k = 0; k < 16; k++) { ar[k]=0.f; ai[k]=0.f; }
    const float* Abase = A + ((size_t)(b*VV + v)*SS)*AESZ + cg*256;
    for (int xb = 0; xb < SS; xb += 8) {
        int nx = (SS - xb < 8) ? (SS - xb) : 8;
        __syncthreads();
        for (int i = threadIdx.x; i < nx*64; i += 256) {
            int xl = i >> 6, r = i & 63;
            ((float4*)sAx)[xl*64 + r] = *(const float4*)&Abase[(size_t)(xb+xl)*AESZ + r*4];
        }
        __syncthreads();
        for (int xl = 0; xl < nx; xl++) {
            int x = xb + xl;
            float2 a = *(const float2*)&sAx[xl*256 + c*32 + ky*2];
            #pragma unroll
            for (int kxl = 0; kxl < 16; kxl++) {
                int kx2 = kxh*16 + kxl;
                float tc = stx[x*64 + kx2*2], ts = stx[x*64 + kx2*2 + 1];
                ar[kxl] += a.x*tc + a.y*ts;
                ai[kxl] += a.y*tc - a.x*ts;
            }
        }
    }
    int ip = (cg*8 + c)*3 + v;
    #pragma unroll
    for (int kxl = 0; kxl < 16; kxl++) {
        int kx = kxh*16 + kxl;
        size_t idx = ((((size_t)b*KX + kx)*MOD + ky)*96 + ip)*2;
        hf[idx] = ar[kxl]; hf[idx+1] = ai[kxl];
    }
}

// ---------------- stage C: mode mixing ----------------
// grid (kxi=32, jqc=6, bg=2). oft[b][jq][kx][ky][2]
__global__ void k_C(const float* __restrict__ hf,
                    const float* __restrict__ w1r, const float* __restrict__ w1i,
                    const float* __restrict__ w2r, const float* __restrict__ w2i,
                    float* __restrict__ oft) {
    int kxi = blockIdx.x;
    int jqc = blockIdx.y;
    int bg  = blockIdx.z;
    int ky  = threadIdx.x & 15;
    int jql = threadIdx.x >> 4;
    int jq  = jqc*16 + jql;
    int j = jq / 3, q = jq % 3;
    const float* wr; const float* wi; int kxm = kxi & 15;
    if (kxi < 16) { wr = w1r; wi = w1i; }
    else          { wr = w2r; wi = w2i; }
    float accr[16], acci[16];
    #pragma unroll
    for (int t = 0; t < 16; t++) { accr[t]=0.f; acci[t]=0.f; }
    __shared__ float2 shf2[8*16*17];   // [ipl][bl][ky pad17]
    int sbl = threadIdx.x & 15;
    int sky = threadIdx.x >> 4;
    for (int ip0 = 0; ip0 < 96; ip0 += 8) {
        __syncthreads();
        {
            const float* gsrc = hf + ((((size_t)(bg*16+sbl)*KX + kxi)*MOD + sky)*96 + ip0)*2;
            #pragma unroll
            for (int u = 0; u < 4; u++) {
                float4 f = *(const float4*)(gsrc + u*4);
                shf2[((u*2  )*16 + sbl)*17 + sky] = make_float2(f.x, f.y);
                shf2[((u*2+1)*16 + sbl)*17 + sky] = make_float2(f.z, f.w);
            }
        }
        __syncthreads();
        #pragma unroll
        for (int ipl = 0; ipl < 8; ipl++) {
            int ip = ip0 + ipl;
            int iw = ip / 3, p = ip % 3;
            size_t widx = (((((size_t)iw*WID + j)*VV + p)*VV + q)*MOD + kxm)*MOD + ky;
            float wrv = wr[widx];
            float wiv = wi[widx];
            #pragma unroll
            for (int bl = 0; bl < 16; bl++) {
                float2 hv = shf2[(ipl*16 + bl)*17 + ky];
                accr[bl] += hv.x * wrv - hv.y * wiv;
                acci[bl] += hv.x * wiv + hv.y * wrv;
            }
        }
    }
    #pragma unroll
    for (int bl = 0; bl < 16; bl++) {
        int b = bg*16 + bl;
        float2* out = (float2*)(oft + ((((size_t)b*96 + jq)*KX + kxi)*MOD + ky)*2);
        *out = make_float2(accr[bl], acci[bl]);
    }
}

// ---------------- stage D: inverse x-DFT ----------------
// grid 3072 (b*96+jq). G[((b*3+v)*106+x)*1024 + j*32 + ky*2]
__global__ void k_D(const float* __restrict__ oft, const float* __restrict__ tabxTr,
                    const float* __restrict__ tabxTi, float* __restrict__ G) {
    int ch = blockIdx.x;
    int b = ch / 96; int jq = ch % 96; int j = jq / 3; int v = jq % 3;
    __shared__ float so[KX*MOD*2];   // [kx][ky][2]
    __shared__ float str[KX*107];
    __shared__ float sti[KX*107];
    const float* src = oft + (size_t)ch * (KX*MOD*2);
    for (int i = threadIdx.x*4; i < KX*MOD*2; i += 1024)
        *(float4*)&so[i] = *(const float4*)&src[i];
    for (int i = threadIdx.x; i < KX*SS; i += 256) {
        int k = i / SS, x = i % SS;
        str[k*107 + x] = tabxTr[i];
        sti[k*107 + x] = tabxTi[i];
    }
    __syncthreads();
    int ky = threadIdx.x & 15;
    int xg = threadIdx.x >> 4;
    float* Gb = G + ((size_t)(b*VV + v)*SS)*AESZ + j*32 + ky*2;
    for (int xx = xg; xx < SS; xx += 16) {
        float gr = 0.f, gi = 0.f;
        #pragma unroll
        for (int k = 0; k < KX; k++) {
            float2 o = *(const float2*)&so[(k*MOD + ky)*2];
            float tc = str[k*107 + xx], ts = sti[k*107 + xx];
            gr += o.x*tc - o.y*ts;
            gi += o.x*ts + o.y*tc;
        }
        *(float2*)(Gb + (size_t)xx*AESZ) = make_float2(gr, gi);
    }
}

// ---------------- stage E: inverse y-DFT + conv + bias (+gelu) + next-layer y-DFT ----------------
// grid B*V*S. Reads G slice + hold row; writes hnew row + A slice (aliased with G).
__global__ void k_E(float* __restrict__ G, const float* __restrict__ hold,
                    const float* __restrict__ taby,
                    const float* __restrict__ cw, const float* __restrict__ cb,
                    float* __restrict__ hnew, int do_gelu, int writeA) {
    int blk = blockIdx.x;
    __shared__ float sG[AESZ];
    __shared__ float sh[SS*33];
    __shared__ float sty[SS*33];
    __shared__ float sE[SS*33];
    __shared__ float scw[WID*WID];
    __shared__ float scb[WID];
    {
        const float* Gs = G + (size_t)blk * AESZ;
        for (int i = threadIdx.x*4; i < AESZ; i += 1024)
            *(float4*)&sG[i] = *(const float4*)&Gs[i];
        const float* hs = hold + (size_t)blk * ROWF;
        for (int i = threadIdx.x*4; i < ROWF; i += 1024)
            *(float4*)&sh[i + (i>>5)] = *(const float4*)&hs[i];
        for (int i = threadIdx.x; i < SS*32; i += 256) sty[(i>>5)*33 + (i&31)] = taby[i];
        for (int i = threadIdx.x; i < WID*WID; i += 256) scw[i] = cw[i];
        if (threadIdx.x < WID) scb[threadIdx.x] = cb[threadIdx.x];
    }
    __syncthreads();
    const float norm = 1.0f / (float)NPIX;
    int y = threadIdx.x & 127;
    int jg = threadIdx.x >> 7;
    if (y < SS) {
        for (int j = jg; j < WID; j += 2) {
            float s = sG[j*32];
            #pragma unroll
            for (int ky = 1; ky < MOD; ky++) {
                s += 2.f * (sG[j*32 + 2*ky] * sty[y*33 + 2*ky]
                          - sG[j*32 + 2*ky + 1] * sty[y*33 + 2*ky + 1]);
            }
            float acc = s * norm + scb[j];
            #pragma unroll
            for (int c = 0; c < WID; c++) acc += sh[y*33 + c] * scw[j*WID + c];
            if (do_gelu) acc = 0.5f * acc * (1.f + erff(acc * 0.70710678118654752440f));
            sE[y*33 + j] = acc;
        }
    }
    __syncthreads();
    float* hbase = hnew + (size_t)blk * ROWF;
    for (int i = threadIdx.x*4; i < ROWF; i += 1024)
        *(float4*)(hbase + i) = *(const float4*)&sE[i + (i>>5)];
    if (writeA) {
        int j = threadIdx.x & 31;
        int kyg = threadIdx.x >> 5;
        float r0=0.f,i0=0.f,r1=0.f,i1=0.f;
        int ky0 = kyg*2;
        for (int yy = 0; yy < SS; yy++) {
            float hv = sE[yy*33 + j];
            float c0 = sty[yy*33 + 2*ky0],   s0 = sty[yy*33 + 2*ky0+1];
            float c1 = sty[yy*33 + 2*ky0+2], s1 = sty[yy*33 + 2*ky0+3];
            r0 += hv*c0; i0 -= hv*s0;
            r1 += hv*c1; i1 -= hv*s1;
        }
        *(float4*)&sG[j*32 + kyg*4] = make_float4(r0, i0, r1, i1);
        __syncthreads();
        float* Abase = G + (size_t)blk * AESZ;   // A aliases G: same slice
        for (int i = threadIdx.x*4; i < AESZ; i += 1024)
            *(float4*)(Abase + i) = *(const float4*)&sG[i];
    }
}

// ---------------- head: fc1 + gelu + fc2 ----------------
__global__ void k_head(const float* __restrict__ h, const float* __restrict__ fc1w,
                       const float* __restrict__ fc1b, const float* __restrict__ fc2w,
                       const float* __restrict__ fc2b, float* __restrict__ out) {
    int blk = blockIdx.x;
    __shared__ float sh[SS*33];
    __shared__ float sw1[WID*128];
    __shared__ float sb1[128];
    __shared__ float sw2[128];
    __shared__ float spart[128*2];
    const float* hs = h + (size_t)blk * ROWF;
    for (int i = threadIdx.x*4; i < ROWF; i += 1024)
        *(float4*)&sh[i + (i>>5)] = *(const float4*)&hs[i];
    for (int i = threadIdx.x*4; i < WID*128; i += 1024)
        *(float4*)&sw1[i] = *(const float4*)&fc1w[i];
    if (threadIdx.x < 128) { sb1[threadIdx.x] = fc1b[threadIdx.x]; sw2[threadIdx.x] = fc2w[threadIdx.x]; }
    __syncthreads();
    int y = threadIdx.x & 127;
    int kh = threadIdx.x >> 7;
    if (y < SS) {
        float hr[WID];
        #pragma unroll
        for (int c = 0; c < WID; c++) hr[c] = sh[y*33 + c];
        float part = 0.f;
        for (int k = kh*64; k < kh*64 + 64; k++) {
            float s = sb1[k];
            #pragma unroll
            for (int c = 0; c < WID; c++) s += hr[c] * sw1[c*128 + k];
            s = 0.5f * s * (1.f + erff(s * 0.70710678118654752440f));
            part += s * sw2[k];
        }
        spart[y*2 + kh] = part;
    }
    __syncthreads();
    if (kh == 0 && y < SS) {
        out[(size_t)blk*SS + y] = spart[y*2] + spart[y*2+1] + fc2b[0];
    }
}

extern "C" void kernel_launch(void* const* d_in, const int* in_sizes, int n_in,
                              void* d_out, int out_size, void* d_ws, size_t ws_size,
                              hipStream_t stream) {
    const float* xin   = (const float*)d_in[0];
    const float* gridx = (const float*)d_in[1];
    const float* gridy = (const float*)d_in[2];
    const float* fc0w  = (const float*)d_in[3];
    const float* fc0b  = (const float*)d_in[4];
    const float* w1r   = (const float*)d_in[5];
    const float* w1i   = (const float*)d_in[6];
    const float* w2r   = (const float*)d_in[7];
    const float* w2i   = (const float*)d_in[8];
    const float* convw = (const float*)d_in[9];
    const float* convb = (const float*)d_in[10];
    const float* fc1w  = (const float*)d_in[11];
    const float* fc1b  = (const float*)d_in[12];
    const float* fc2w  = (const float*)d_in[13];
    const float* fc2b  = (const float*)d_in[14];
    float* out = (float*)d_out;

    float* p = (float*)d_ws;
    float* taby   = p; p += SS*MOD*2;
    float* tabx   = p; p += SS*KX*2;
    float* tabxTr = p; p += SS*KX;
    float* tabxTi = p; p += SS*KX;
    float* h0   = p; p += (size_t)BB*VV*SS*ROWF;     // 34.5M floats
    float* h1   = p; p += (size_t)BB*VV*SS*ROWF;
    float* AG   = p; p += (size_t)BB*VV*SS*AESZ;     // A aliased with G
    float* hfb  = p; p += (size_t)BB*KX*MOD*96*2;
    float* oftb = p; p += (size_t)BB*96*KX*MOD*2;

    k_tables<<<14, 256, 0, stream>>>(taby, tabx, tabxTr, tabxTi);
    k_fc0A<<<BB*VV*SS, 256, 0, stream>>>(xin, gridx, gridy, fc0w, fc0b, taby, h0, AG);

    float* hc = h0; float* hn = h1;
    for (int L = 0; L < NL; L++) {
        k_B<<<BB*VV*4, 256, 0, stream>>>(AG, tabx, hfb);
        k_C<<<dim3(KX, 6, 2), 256, 0, stream>>>(hfb,
            w1r + (size_t)L*WLAYER, w1i + (size_t)L*WLAYER,
            w2r + (size_t)L*WLAYER, w2i + (size_t)L*WLAYER, oftb);
        k_D<<<BB*96, 256, 0, stream>>>(oftb, tabxTr, tabxTi, AG);
        k_E<<<BB*VV*SS, 256, 0, stream>>>(AG, hc, taby,
            convw + (size_t)L*WID*WID, convb + (size_t)L*WID, hn,
            (L < 3) ? 1 : 0, (L < NL-1) ? 1 : 0);
        float* tmp = hc; hc = hn; hn = tmp;
    }
    k_head<<<BB*VV*SS, 256, 0, stream>>>(hc, fc1w, fc1b, fc2w, fc2b, out);
}

// Round 3
// 5262.418 us; speedup vs baseline: 1.5500x; 1.0472x over previous
//
#include <hip/hip_runtime.h>
#include <math.h>

#define BB 32
#define VV 3
#define SS 106
#define TIN 30
#define WID 32
#define MOD 16
#define NL 6
#define NPIX (SS*SS)
#define KX 32
#define WLAYER (WID*WID*VV*VV*MOD*MOD)
#define ROWF (SS*WID)          // 3392 floats per (b,v,x) row of h
#define AESZ 1024              // floats per (b,v,x) slice of A/G
#define TWO_PI_F 6.2831853071795864769f

// ---------------- fc0 (lift) + forward y-DFT ----------------
// grid B*V*S (b,v,xr). h channel-last: h[blk*3392 + y*32 + c]
// A[blk*1024 + c*32 + ky*2 + ri]
__global__ void k_fc0A(const float* __restrict__ xin, const float* __restrict__ gridx,
                       const float* __restrict__ gridy, const float* __restrict__ fw,
                       const float* __restrict__ fb,
                       float* __restrict__ h, float* __restrict__ A) {
    int blk = blockIdx.x;
    int xr = blk % SS; int bv = blk / SS; int v = bv % VV; int b = bv / VV;
    __shared__ float sx[SS*31];     // [y][30] pad 31, 13.1 KB
    __shared__ float sw[32*WID];    // 4 KB
    __shared__ float sE[SS*33];     // 13.7 KB
    __shared__ float sb[WID];
    __shared__ float2 tw[112];      // e^{2pi i m/106}
    const float* xrow = xin + ((size_t)(b*VV + v)*SS + xr) * (size_t)(SS*TIN);
    for (int i = threadIdx.x; i < SS*TIN; i += 256) sx[(i/30)*31 + (i%30)] = xrow[i];
    for (int i = threadIdx.x; i < 32*WID; i += 256) sw[i] = fw[i];
    if (threadIdx.x < WID) sb[threadIdx.x] = fb[threadIdx.x];
    if (threadIdx.x < SS) {
        float ang = TWO_PI_F * (float)threadIdx.x / (float)SS;
        tw[threadIdx.x] = make_float2(cosf(ang), sinf(ang));
    }
    __syncthreads();
    float gx = gridx[xr];
    int y = threadIdx.x & 127;
    int wg = threadIdx.x >> 7;
    if (y < SS) {
        float gy = gridy[y];
        for (int w = wg; w < WID; w += 2) {
            float acc = sb[w] + gx * sw[30*WID + w] + gy * sw[31*WID + w];
            #pragma unroll
            for (int t = 0; t < TIN; t++) acc += sx[y*31 + t] * sw[t*WID + w];
            sE[y*33 + w] = acc;
        }
    }
    __syncthreads();
    float* hbase = h + (size_t)blk * ROWF;
    for (int i = threadIdx.x*4; i < ROWF; i += 1024)
        *(float4*)(hbase + i) = *(const float4*)&sE[i + (i>>5)];
    // forward y-DFT
    {
        int j = threadIdx.x & 31;
        int kyg = threadIdx.x >> 5;   // 0..7
        int ky0 = kyg*2;
        float r0=0.f,i0=0.f,r1=0.f,i1=0.f;
        int m0 = 0, m1 = 0;
        for (int yy = 0; yy < SS; yy++) {
            float hv = sE[yy*33 + j];
            float2 t0 = tw[m0];
            float2 t1 = tw[m1];
            r0 += hv*t0.x; i0 -= hv*t0.y;
            r1 += hv*t1.x; i1 -= hv*t1.y;
            m0 += ky0;   if (m0 >= SS) m0 -= SS;
            m1 += ky0+1; if (m1 >= SS) m1 -= SS;
        }
        *(float4*)&sx[j*32 + kyg*4] = make_float4(r0, i0, r1, i1);
    }
    __syncthreads();
    float* Abase = A + (size_t)blk * AESZ;
    for (int i = threadIdx.x*4; i < AESZ; i += 1024)
        *(float4*)(Abase + i) = *(const float4*)&sx[i];
}

// ---------------- stage B: forward x-DFT ----------------
// grid 768: blk -> cg(8), v(3), b(32). block 128. hf[b][kx][ky][ip][2]
__global__ void k_B(const float* __restrict__ A, float* __restrict__ hf) {
    int blk = blockIdx.x;
    int cg = blk & 7; int v = (blk >> 3) % 3; int b = blk / 24;
    __shared__ float stx[SS*64];    // [x][k][2] 27.1 KB
    __shared__ float sAx[8*128];    // 8 x-rows of [c4][ky][2], 4 KB
    __shared__ float2 tw[112];
    if (threadIdx.x < SS) {
        float ang = TWO_PI_F * (float)threadIdx.x / (float)SS;
        tw[threadIdx.x] = make_float2(cosf(ang), sinf(ang));
    }
    __syncthreads();
    for (int i = threadIdx.x; i < SS*KX; i += 128) {
        int x = i >> 5, k = i & 31;
        int kxv = (k < 16) ? k : (k + 74);
        int m = (x * kxv) % SS;
        float2 t = tw[m];
        stx[i*2] = t.x; stx[i*2+1] = t.y;
    }
    int kxh = threadIdx.x >> 6;        // 0..1
    int ky  = (threadIdx.x >> 2) & 15;
    int c   = threadIdx.x & 3;
    float ar[16], ai[16];
    #pragma unroll
    for (int k = 0; k < 16; k++) { ar[k]=0.f; ai[k]=0.f; }
    const float* Abase = A + ((size_t)(b*VV + v)*SS)*AESZ + cg*128;
    for (int xb = 0; xb < SS; xb += 8) {
        int nx = (SS - xb < 8) ? (SS - xb) : 8;
        __syncthreads();
        for (int i = threadIdx.x; i < nx*32; i += 128) {
            int xl = i >> 5, r = i & 31;
            ((float4*)sAx)[xl*32 + r] = *(const float4*)&Abase[(size_t)(xb+xl)*AESZ + r*4];
        }
        __syncthreads();
        for (int xl = 0; xl < nx; xl++) {
            int x = xb + xl;
            float2 a = *(const float2*)&sAx[xl*128 + c*32 + ky*2];
            #pragma unroll
            for (int kxl = 0; kxl < 16; kxl++) {
                int kx2 = kxh*16 + kxl;
                float tc = stx[x*64 + kx2*2], ts = stx[x*64 + kx2*2 + 1];
                ar[kxl] += a.x*tc + a.y*ts;
                ai[kxl] += a.y*tc - a.x*ts;
            }
        }
    }
    int ip = (cg*4 + c)*3 + v;
    #pragma unroll
    for (int kxl = 0; kxl < 16; kxl++) {
        int kx = kxh*16 + kxl;
        size_t idx = ((((size_t)b*KX + kx)*MOD + ky)*96 + ip)*2;
        hf[idx] = ar[kxl]; hf[idx+1] = ai[kxl];
    }
}

// ---------------- stage C: mode mixing ----------------
// grid (kxi=32, jqc=6, bg=2). oft[b][jq][kx][ky][2]
__global__ void k_C(const float* __restrict__ hf,
                    const float* __restrict__ w1r, const float* __restrict__ w1i,
                    const float* __restrict__ w2r, const float* __restrict__ w2i,
                    float* __restrict__ oft) {
    int kxi = blockIdx.x;
    int jqc = blockIdx.y;
    int bg  = blockIdx.z;
    int ky  = threadIdx.x & 15;
    int jql = threadIdx.x >> 4;
    int jq  = jqc*16 + jql;
    int j = jq / 3, q = jq % 3;
    const float* wr; const float* wi; int kxm = kxi & 15;
    if (kxi < 16) { wr = w1r; wi = w1i; }
    else          { wr = w2r; wi = w2i; }
    float accr[16], acci[16];
    #pragma unroll
    for (int t = 0; t < 16; t++) { accr[t]=0.f; acci[t]=0.f; }
    __shared__ float2 shf2[8*16*17];   // [ipl][bl][ky pad17]
    int sbl = threadIdx.x & 15;
    int sky = threadIdx.x >> 4;
    for (int ip0 = 0; ip0 < 96; ip0 += 8) {
        __syncthreads();
        {
            const float* gsrc = hf + ((((size_t)(bg*16+sbl)*KX + kxi)*MOD + sky)*96 + ip0)*2;
            #pragma unroll
            for (int u = 0; u < 4; u++) {
                float4 f = *(const float4*)(gsrc + u*4);
                shf2[((u*2  )*16 + sbl)*17 + sky] = make_float2(f.x, f.y);
                shf2[((u*2+1)*16 + sbl)*17 + sky] = make_float2(f.z, f.w);
            }
        }
        __syncthreads();
        #pragma unroll
        for (int ipl = 0; ipl < 8; ipl++) {
            int ip = ip0 + ipl;
            int iw = ip / 3, p = ip % 3;
            size_t widx = (((((size_t)iw*WID + j)*VV + p)*VV + q)*MOD + kxm)*MOD + ky;
            float wrv = wr[widx];
            float wiv = wi[widx];
            #pragma unroll
            for (int bl = 0; bl < 16; bl++) {
                float2 hv = shf2[(ipl*16 + bl)*17 + ky];
                accr[bl] += hv.x * wrv - hv.y * wiv;
                acci[bl] += hv.x * wiv + hv.y * wrv;
            }
        }
    }
    #pragma unroll
    for (int bl = 0; bl < 16; bl++) {
        int b = bg*16 + bl;
        float2* out = (float2*)(oft + ((((size_t)b*96 + jq)*KX + kxi)*MOD + ky)*2);
        *out = make_float2(accr[bl], acci[bl]);
    }
}

// ---------------- stage D: inverse x-DFT ----------------
// grid 3072 (b*96+jq). G[((b*3+v)*106+x)*1024 + j*32 + ky*2]
__global__ void k_D(const float* __restrict__ oft, float* __restrict__ G) {
    int ch = blockIdx.x;
    int b = ch / 96; int jq = ch % 96; int j = jq / 3; int v = jq % 3;
    __shared__ float so[KX*MOD*2];   // 4 KB
    __shared__ float str[KX*107];    // 13.7 KB
    __shared__ float sti[KX*107];    // 13.7 KB
    __shared__ float2 tw[112];
    if (threadIdx.x < SS) {
        float ang = TWO_PI_F * (float)threadIdx.x / (float)SS;
        tw[threadIdx.x] = make_float2(cosf(ang), sinf(ang));
    }
    const float* src = oft + (size_t)ch * (KX*MOD*2);
    for (int i = threadIdx.x*4; i < KX*MOD*2; i += 1024)
        *(float4*)&so[i] = *(const float4*)&src[i];
    __syncthreads();
    for (int i = threadIdx.x; i < KX*SS; i += 256) {
        int k = i / SS, x = i % SS;
        int kxv = (k < 16) ? k : (k + 74);
        int m = (x * kxv) % SS;
        float2 t = tw[m];
        str[k*107 + x] = t.x;
        sti[k*107 + x] = t.y;
    }
    __syncthreads();
    int ky = threadIdx.x & 15;
    int xg = threadIdx.x >> 4;
    float* Gb = G + ((size_t)(b*VV + v)*SS)*AESZ + j*32 + ky*2;
    for (int xx = xg; xx < SS; xx += 16) {
        float gr = 0.f, gi = 0.f;
        #pragma unroll
        for (int k = 0; k < KX; k++) {
            float2 o = *(const float2*)&so[(k*MOD + ky)*2];
            float tc = str[k*107 + xx], ts = sti[k*107 + xx];
            gr += o.x*tc - o.y*ts;
            gi += o.x*ts + o.y*tc;
        }
        *(float2*)(Gb + (size_t)xx*AESZ) = make_float2(gr, gi);
    }
}

// ---------------- stage E: inverse y-DFT + conv + bias (+gelu) + next y-DFT ----------------
// grid B*V*S. LDS 23.3 KB -> ~6 blocks/CU.
__global__ void k_E(float* __restrict__ G, const float* __restrict__ hold,
                    const float* __restrict__ cw, const float* __restrict__ cb,
                    float* __restrict__ hnew, int do_gelu, int writeA) {
    int blk = blockIdx.x;
    __shared__ float sG[AESZ];        // 4 KB
    __shared__ float sE[SS*33];       // 13.7 KB
    __shared__ float scw[WID*WID];    // 4 KB
    __shared__ float scb[WID];
    __shared__ float2 tw[112];
    {
        const float* Gs = G + (size_t)blk * AESZ;
        for (int i = threadIdx.x*4; i < AESZ; i += 1024)
            *(float4*)&sG[i] = *(const float4*)&Gs[i];
        for (int i = threadIdx.x*4; i < WID*WID; i += 1024)
            *(float4*)&scw[i] = *(const float4*)&cw[i];
        if (threadIdx.x < WID) scb[threadIdx.x] = cb[threadIdx.x];
        if (threadIdx.x < SS) {
            float ang = TWO_PI_F * (float)threadIdx.x / (float)SS;
            tw[threadIdx.x] = make_float2(cosf(ang), sinf(ang));
        }
    }
    int y = threadIdx.x & 127;
    int jg = threadIdx.x >> 7;
    float hreg[32];
    if (y < SS) {
        const float4* hs = (const float4*)(hold + (size_t)blk * ROWF + (size_t)y*32);
        #pragma unroll
        for (int u = 0; u < 8; u++) {
            float4 f = hs[u];
            hreg[u*4]=f.x; hreg[u*4+1]=f.y; hreg[u*4+2]=f.z; hreg[u*4+3]=f.w;
        }
    }
    __syncthreads();
    const float norm = 1.0f / (float)NPIX;
    if (y < SS) {
        for (int j = jg; j < WID; j += 2) {
            float s = sG[j*32];
            int m = 0;
            #pragma unroll
            for (int ky = 1; ky < MOD; ky++) {
                m += y; if (m >= SS) m -= SS;
                float2 t = tw[m];
                s += 2.f * (sG[j*32 + 2*ky] * t.x - sG[j*32 + 2*ky + 1] * t.y);
            }
            float acc = s * norm + scb[j];
            #pragma unroll
            for (int c = 0; c < WID; c++) acc += hreg[c] * scw[j*WID + c];
            if (do_gelu) acc = 0.5f * acc * (1.f + erff(acc * 0.70710678118654752440f));
            sE[y*33 + j] = acc;
        }
    }
    __syncthreads();
    float* hbase = hnew + (size_t)blk * ROWF;
    for (int i = threadIdx.x*4; i < ROWF; i += 1024)
        *(float4*)(hbase + i) = *(const float4*)&sE[i + (i>>5)];
    if (writeA) {
        int j = threadIdx.x & 31;
        int kyg = threadIdx.x >> 5;
        int ky0 = kyg*2;
        float r0=0.f,i0=0.f,r1=0.f,i1=0.f;
        int m0 = 0, m1 = 0;
        for (int yy = 0; yy < SS; yy++) {
            float hv = sE[yy*33 + j];
            float2 t0 = tw[m0];
            float2 t1 = tw[m1];
            r0 += hv*t0.x; i0 -= hv*t0.y;
            r1 += hv*t1.x; i1 -= hv*t1.y;
            m0 += ky0;   if (m0 >= SS) m0 -= SS;
            m1 += ky0+1; if (m1 >= SS) m1 -= SS;
        }
        __syncthreads();
        *(float4*)&sG[j*32 + kyg*4] = make_float4(r0, i0, r1, i1);
        __syncthreads();
        float* Abase = G + (size_t)blk * AESZ;
        for (int i = threadIdx.x*4; i < AESZ; i += 1024)
            *(float4*)(Abase + i) = *(const float4*)&sG[i];
    }
}

// ---------------- head: fc1 + gelu + fc2 ----------------
__global__ void k_head(const float* __restrict__ h, const float* __restrict__ fc1w,
                       const float* __restrict__ fc1b, const float* __restrict__ fc2w,
                       const float* __restrict__ fc2b, float* __restrict__ out) {
    int blk = blockIdx.x;
    __shared__ float sh[SS*33];
    __shared__ float sw1[WID*128];
    __shared__ float sb1[128];
    __shared__ float sw2[128];
    __shared__ float spart[128*2];
    const float* hs = h + (size_t)blk * ROWF;
    for (int i = threadIdx.x*4; i < ROWF; i += 1024)
        *(float4*)&sh[i + (i>>5)] = *(const float4*)&hs[i];
    for (int i = threadIdx.x*4; i < WID*128; i += 1024)
        *(float4*)&sw1[i] = *(const float4*)&fc1w[i];
    if (threadIdx.x < 128) { sb1[threadIdx.x] = fc1b[threadIdx.x]; sw2[threadIdx.x] = fc2w[threadIdx.x]; }
    __syncthreads();
    int y = threadIdx.x & 127;
    int kh = threadIdx.x >> 7;
    if (y < SS) {
        float hr[WID];
        #pragma unroll
        for (int c = 0; c < WID; c++) hr[c] = sh[y*33 + c];
        float part = 0.f;
        for (int k = kh*64; k < kh*64 + 64; k++) {
            float s = sb1[k];
            #pragma unroll
            for (int c = 0; c < WID; c++) s += hr[c] * sw1[c*128 + k];
            s = 0.5f * s * (1.f + erff(s * 0.70710678118654752440f));
            part += s * sw2[k];
        }
        spart[y*2 + kh] = part;
    }
    __syncthreads();
    if (kh == 0 && y < SS) {
        out[(size_t)blk*SS + y] = spart[y*2] + spart[y*2+1] + fc2b[0];
    }
}

extern "C" void kernel_launch(void* const* d_in, const int* in_sizes, int n_in,
                              void* d_out, int out_size, void* d_ws, size_t ws_size,
                              hipStream_t stream) {
    const float* xin   = (const float*)d_in[0];
    const float* gridx = (const float*)d_in[1];
    const float* gridy = (const float*)d_in[2];
    const float* fc0w  = (const float*)d_in[3];
    const float* fc0b  = (const float*)d_in[4];
    const float* w1r   = (const float*)d_in[5];
    const float* w1i   = (const float*)d_in[6];
    const float* w2r   = (const float*)d_in[7];
    const float* w2i   = (const float*)d_in[8];
    const float* convw = (const float*)d_in[9];
    const float* convb = (const float*)d_in[10];
    const float* fc1w  = (const float*)d_in[11];
    const float* fc1b  = (const float*)d_in[12];
    const float* fc2w  = (const float*)d_in[13];
    const float* fc2b  = (const float*)d_in[14];
    float* out = (float*)d_out;

    float* p = (float*)d_ws;
    float* h0   = p; p += (size_t)BB*VV*SS*ROWF;
    float* h1   = p; p += (size_t)BB*VV*SS*ROWF;
    float* AG   = p; p += (size_t)BB*VV*SS*AESZ;     // A aliased with G
    float* hfb  = p; p += (size_t)BB*KX*MOD*96*2;
    float* oftb = p; p += (size_t)BB*96*KX*MOD*2;

    k_fc0A<<<BB*VV*SS, 256, 0, stream>>>(xin, gridx, gridy, fc0w, fc0b, h0, AG);

    float* hc = h0; float* hn = h1;
    for (int L = 0; L < NL; L++) {
        k_B<<<BB*VV*8, 128, 0, stream>>>(AG, hfb);
        k_C<<<dim3(KX, 6, 2), 256, 0, stream>>>(hfb,
            w1r + (size_t)L*WLAYER, w1i + (size_t)L*WLAYER,
            w2r + (size_t)L*WLAYER, w2i + (size_t)L*WLAYER, oftb);
        k_D<<<BB*96, 256, 0, stream>>>(oftb, AG);
        k_E<<<BB*VV*SS, 256, 0, stream>>>(AG, hc,
            convw + (size_t)L*WID*WID, convb + (size_t)L*WID, hn,
            (L < 3) ? 1 : 0, (L < NL-1) ? 1 : 0);
        float* tmp = hc; hc = hn; hn = tmp;
    }
    k_head<<<BB*VV*SS, 256, 0, stream>>>(hc, fc1w, fc1b, fc2w, fc2b, out);
}